// Round 13
// baseline (221.233 us; speedup 1.0000x reference)
//
#include <hip/hip_runtime.h>
#include <math.h>

#define NAG 8
#define NE  16
#define ED  64
#define HYPD 128
#define QKVW 384
#define SB 2            // 2 samples x 2 hyps per iteration; 2 iterations

#define X1S 132
#define KS  132
#define QS  132

// LDS layout (bytes). "virtual sample" v = j*2+s (j = hyp-in-pair, s = sample):
//  x1    @ 0     : 64*132*2 = 16896  (overlays: slog f32[2048] @0..8192, attn[32][132] @8448..16896)
//  k     @ 16896 : 64*132*2 = 16896  (attn2[32][132] overlays @16896; k dead after P3a)
//  q     @ 33792 : 32*132*2 = 8448
//  out0  @ 42240 : 16*32*2  = 1024
//  means @ 43264 : 3*2*32*4 = 768
//  em    @ 44032 : 32*4     = 128
#define OFF_X1    0
#define OFF_SLOG  0
#define OFF_ATTN  8448
#define OFF_K     16896
#define OFF_ATTN2 16896
#define OFF_Q     33792
#define OFF_OUT0  42240
#define OFF_MEANS 43264
#define OFF_EM    44032
#define LDS_BYTES 44160

typedef __attribute__((ext_vector_type(8))) short bf16x8;
typedef __attribute__((ext_vector_type(4))) short bf16x4;
typedef __attribute__((ext_vector_type(4))) float f32x4;

__device__ __forceinline__ short f2bf(float f) {
    union { float f; unsigned u; } c; c.f = f;
    unsigned r = (c.u + 0x7FFFu + ((c.u >> 16) & 1u)) >> 16;
    return (short)r;
}
__device__ __forceinline__ float bf2f(short s) {
    union { unsigned u; float f; } c; c.u = ((unsigned)(unsigned short)s) << 16; return c.f;
}
__device__ __forceinline__ bf16x8 ld_frag(const short* p) {
    bf16x4 lo = *(const bf16x4*)p;
    bf16x4 hi = *(const bf16x4*)(p + 16);
    return __builtin_shufflevector(lo, hi, 0, 1, 2, 3, 4, 5, 6, 7);
}

// ---------------- weight packing: fp32 -> bf16 MFMA B-fragments -------------
// slot map: fc1 [0,64) = h*16+nt*2+kt ; attn [64,448) = 64+h*96+nt*4+kt ;
//           out [448,576) = 448+h*32+nt*4+kt ; fc2 [576,608) = 576+h*8+nt*4+kt
// frag elem j of lane l: k = kt*32 + 4*(l>>4) + (j&3) + 16*(j>>2), n = nt*16 + (l&15)
__global__ void pack_weights(const float* __restrict__ fc1_w,
                             const float* __restrict__ attn_w,
                             const float* __restrict__ out_w,
                             const float* __restrict__ fc2_w,
                             short* __restrict__ ws) {
    int gid = blockIdx.x * 256 + threadIdx.x;
    if (gid >= 608 * 64) return;
    int slot = gid >> 6, l = gid & 63;
    const float* src; int N, nt, kt;
    if (slot < 64) {
        int h = slot >> 4, f = slot & 15;
        nt = f >> 1; kt = f & 1; N = HYPD; src = fc1_w + h * ED * HYPD;
    } else if (slot < 448) {
        int s2 = slot - 64; int h = s2 / 96, f = s2 % 96;
        nt = f >> 2; kt = f & 3; N = QKVW; src = attn_w + h * HYPD * QKVW;
    } else if (slot < 576) {
        int s2 = slot - 448; int h = s2 >> 5, f = s2 & 31;
        nt = f >> 2; kt = f & 3; N = HYPD; src = out_w + h * HYPD * HYPD;
    } else {
        int s2 = slot - 576; int h = s2 >> 3, f = s2 & 7;
        nt = f >> 2; kt = f & 3; N = 32; src = fc2_w + h * HYPD * 32;
    }
    int rg = l >> 4, lc = l & 15;
    bf16x8 fr;
    #pragma unroll
    for (int j = 0; j < 8; ++j) {
        int k = kt * 32 + 4 * rg + (j & 3) + 16 * (j >> 2);
        fr[j] = f2bf(src[k * N + nt * 16 + lc]);
    }
    ((bf16x8*)ws)[slot * 64 + l] = fr;
}

// --------- fused MFMA kernel: 2 samples x 4 hyps / block, 256 threads -------
// 2 outer iterations; each iteration processes hyps {2i, 2i+1} for both samples
// via virtual samples v = j*2 + s (j-major so each 16-row M-tile is one hyp).
__global__ __launch_bounds__(256, 2) void flexq_mfma(
    const float* __restrict__ agent_qs,
    const float* __restrict__ entities,
    const int*   __restrict__ entity_mask,
    const float* __restrict__ fc1_b,
    const float* __restrict__ out_b,
    const float* __restrict__ fc2_b,
    const short* __restrict__ wfrag,
    float* __restrict__ out, int B)
{
    __shared__ __align__(16) char smem[LDS_BYTES];
    short* x1    = (short*)(smem + OFF_X1);
    float* slog  = (float*)(smem + OFF_SLOG);
    short* attn  = (short*)(smem + OFF_ATTN);
    short* k     = (short*)(smem + OFF_K);
    short* attn2 = (short*)(smem + OFF_ATTN2);
    short* q     = (short*)(smem + OFF_Q);
    short* out0  = (short*)(smem + OFF_OUT0);
    float* means = (float*)(smem + OFF_MEANS);
    float* em    = (float*)(smem + OFF_EM);

    const int tid = threadIdx.x;
    const int l = tid & 63, w = tid >> 6;        // 4 waves
    const int rg = l >> 4, lc = l & 15;
    const int b2 = blockIdx.x * SB;
    const bf16x8* WF = (const bf16x8*)wfrag;

    if (tid < 32)
        em[tid] = (entity_mask[(size_t)b2 * NE + tid] != 0) ? 1.0f : 0.0f;

    // entity A-fragments for the 2 samples, held in registers across all hyps
    bf16x8 aent[2][2];
    #pragma unroll
    for (int kt = 0; kt < 2; ++kt)
        #pragma unroll
        for (int s = 0; s < 2; ++s) {
            const float* ap = entities + ((size_t)(b2 + s) * NE + lc) * ED + kt * 32 + rg * 4;
            float4 lo = *(const float4*)ap;
            float4 hi = *(const float4*)(ap + 16);
            bf16x8 af;
            af[0]=f2bf(lo.x); af[1]=f2bf(lo.y); af[2]=f2bf(lo.z); af[3]=f2bf(lo.w);
            af[4]=f2bf(hi.x); af[5]=f2bf(hi.y); af[6]=f2bf(hi.z); af[7]=f2bf(hi.w);
            aent[kt][s] = af;
        }
    __syncthreads();

    for (int i = 0; i < 2; ++i) {               // hyp pair {2i, 2i+1}
        // ---------- P1: x1[v] = relu(ent[s] @ fc1_w[2i+j] + b); wave w owns nt {2w,2w+1} ----------
        {
            f32x4 acc[4][2];                     // [v][n]
            #pragma unroll
            for (int v = 0; v < 4; ++v) {
                acc[v][0] = (f32x4){0.f,0.f,0.f,0.f};
                acc[v][1] = (f32x4){0.f,0.f,0.f,0.f};
            }
            __builtin_amdgcn_s_setprio(1);
            #pragma unroll
            for (int kt = 0; kt < 2; ++kt)
                #pragma unroll
                for (int j = 0; j < 2; ++j) {
                    int hyp = 2*i + j;
                    bf16x8 b0 = WF[(hyp*16 + (2*w+0)*2 + kt)*64 + l];
                    bf16x8 b1 = WF[(hyp*16 + (2*w+1)*2 + kt)*64 + l];
                    #pragma unroll
                    for (int s = 0; s < 2; ++s) {
                        int v = j*2 + s;
                        acc[v][0] = __builtin_amdgcn_mfma_f32_16x16x32_bf16(aent[kt][s], b0, acc[v][0], 0,0,0);
                        acc[v][1] = __builtin_amdgcn_mfma_f32_16x16x32_bf16(aent[kt][s], b1, acc[v][1], 0,0,0);
                    }
                }
            __builtin_amdgcn_s_setprio(0);
            #pragma unroll
            for (int j = 0; j < 2; ++j) {
                float bias0 = fc1_b[(2*i+j)*HYPD + 32*w + lc];
                float bias1 = fc1_b[(2*i+j)*HYPD + 32*w + 16 + lc];
                #pragma unroll
                for (int s = 0; s < 2; ++s) {
                    int v = j*2 + s;
                    #pragma unroll
                    for (int r = 0; r < 4; ++r) {
                        int row = 16*v + 4*rg + r;
                        x1[row*X1S + 32*w + lc]      = f2bf(fmaxf(acc[v][0][r] + bias0, 0.f));
                        x1[row*X1S + 32*w + 16 + lc] = f2bf(fmaxf(acc[v][1][r] + bias1, 0.f));
                    }
                }
            }
        }
        __syncthreads();

        // ---------- P2: qkv[v] = x1[v] @ attn_w[2i+j]; interleaved nt; V in registers ----------
        f32x4 accv[4][2];   // V-tile accumulators per v (nt = w+16, w+20), live through P3
        // half 1: nt {w, w+4, w+8}  (q, q, k)
        {
            f32x4 acc[4][3];
            #pragma unroll
            for (int v = 0; v < 4; ++v)
                #pragma unroll
                for (int n = 0; n < 3; ++n) acc[v][n] = (f32x4){0.f,0.f,0.f,0.f};
            __builtin_amdgcn_s_setprio(1);
            #pragma unroll
            for (int kt = 0; kt < 4; ++kt)
                #pragma unroll
                for (int j = 0; j < 2; ++j) {
                    int hyp = 2*i + j;
                    bf16x8 b0 = WF[(64 + hyp*96 + (w +  0)*4 + kt)*64 + l];
                    bf16x8 b1 = WF[(64 + hyp*96 + (w +  4)*4 + kt)*64 + l];
                    bf16x8 b2 = WF[(64 + hyp*96 + (w +  8)*4 + kt)*64 + l];
                    #pragma unroll
                    for (int s = 0; s < 2; ++s) {
                        int v = j*2 + s;
                        bf16x8 a = ld_frag(x1 + (16*v + lc)*X1S + kt*32 + rg*4);
                        acc[v][0] = __builtin_amdgcn_mfma_f32_16x16x32_bf16(a, b0, acc[v][0], 0,0,0);
                        acc[v][1] = __builtin_amdgcn_mfma_f32_16x16x32_bf16(a, b1, acc[v][1], 0,0,0);
                        acc[v][2] = __builtin_amdgcn_mfma_f32_16x16x32_bf16(a, b2, acc[v][2], 0,0,0);
                    }
                }
            __builtin_amdgcn_s_setprio(0);
            #pragma unroll
            for (int v = 0; v < 4; ++v)
                #pragma unroll
                for (int r = 0; r < 4; ++r) {
                    if (rg < 2) {   // q tiles: agent rows only
                        q[(v*NAG + 4*rg + r)*QS + (w+0)*16 + lc] = f2bf(acc[v][0][r]);
                        q[(v*NAG + 4*rg + r)*QS + (w+4)*16 + lc] = f2bf(acc[v][1][r]);
                    }
                    k[(16*v + 4*rg + r)*KS + w*16 + lc] = f2bf(acc[v][2][r]);   // nt=w+8 -> kcol w
                }
        }
        // half 2: nt {w+12, w+16, w+20}  (k, v, v)
        {
            f32x4 acck[4];
            #pragma unroll
            for (int v = 0; v < 4; ++v) {
                acck[v] = (f32x4){0.f,0.f,0.f,0.f};
                accv[v][0] = (f32x4){0.f,0.f,0.f,0.f};
                accv[v][1] = (f32x4){0.f,0.f,0.f,0.f};
            }
            __builtin_amdgcn_s_setprio(1);
            #pragma unroll
            for (int kt = 0; kt < 4; ++kt)
                #pragma unroll
                for (int j = 0; j < 2; ++j) {
                    int hyp = 2*i + j;
                    bf16x8 b0 = WF[(64 + hyp*96 + (w + 12)*4 + kt)*64 + l];
                    bf16x8 b1 = WF[(64 + hyp*96 + (w + 16)*4 + kt)*64 + l];
                    bf16x8 b2 = WF[(64 + hyp*96 + (w + 20)*4 + kt)*64 + l];
                    #pragma unroll
                    for (int s = 0; s < 2; ++s) {
                        int v = j*2 + s;
                        bf16x8 a = ld_frag(x1 + (16*v + lc)*X1S + kt*32 + rg*4);
                        acck[v]    = __builtin_amdgcn_mfma_f32_16x16x32_bf16(a, b0, acck[v], 0,0,0);
                        accv[v][0] = __builtin_amdgcn_mfma_f32_16x16x32_bf16(a, b1, accv[v][0], 0,0,0);
                        accv[v][1] = __builtin_amdgcn_mfma_f32_16x16x32_bf16(a, b2, accv[v][1], 0,0,0);
                    }
                }
            __builtin_amdgcn_s_setprio(0);
            #pragma unroll
            for (int v = 0; v < 4; ++v)
                #pragma unroll
                for (int r = 0; r < 4; ++r)
                    k[(16*v + 4*rg + r)*KS + (w+4)*16 + lc] = f2bf(acck[v][r]);  // nt=w+12 -> kcol w+4
        }
        __syncthreads();

        // ---------- P3a: logits via MFMA; wave w owns (v,h) pairs 4w..4w+3 ----------
        {
            __builtin_amdgcn_s_setprio(1);
            #pragma unroll
            for (int pp = 0; pp < 4; ++pp) {
                int p = 4*w + pp, v = p >> 2, h = p & 3;
                bf16x8 a  = ld_frag(q + (v*NAG + (lc & 7))*QS + h*32 + rg*4);
                bf16x8 bb = ld_frag(k + (v*NE  + lc)*KS       + h*32 + rg*4);
                f32x4 acc = (f32x4){0.f,0.f,0.f,0.f};
                acc = __builtin_amdgcn_mfma_f32_16x16x32_bf16(a, bb, acc, 0,0,0);
                if (rg < 2) {
                    #pragma unroll
                    for (int r = 0; r < 4; ++r)
                        slog[((v*4 + h)*NAG + 4*rg + r)*16 + lc] = acc[r] * 0.17677669529663687f;
                }
            }
            __builtin_amdgcn_s_setprio(0);
        }
        __syncthreads();

        // ---------- P3b: masked softmax (verified serial path, 128 rows) ----------
        if (tid < 128) {
            int v = tid >> 5, h = (tid >> 3) & 3, qi = tid & 7;
            int s = v & 1;
            float am = em[s*NE + qi];
            float* rowp = slog + ((v*4 + h)*NAG + qi)*16;
            float mx = -3.0e38f; bool any = false;
            #pragma unroll
            for (int kk = 0; kk < NE; ++kk)
                if (em[s*NE + kk] == 0.f) { any = true; mx = fmaxf(mx, rowp[kk]); }
            if (am != 0.f || !any) {
                #pragma unroll
                for (int kk = 0; kk < NE; ++kk) rowp[kk] = 0.f;
            } else {
                float eb[NE]; float sum = 0.f;
                #pragma unroll
                for (int kk = 0; kk < NE; ++kk) {
                    float e = (em[s*NE + kk] == 0.f) ? __expf(rowp[kk] - mx) : 0.f;
                    eb[kk] = e; sum += e;
                }
                float inv = 1.f / sum;
                #pragma unroll
                for (int kk = 0; kk < NE; ++kk) rowp[kk] = eb[kk] * inv;
            }
        }
        __syncthreads();

        // ---------- P3c: PV via MFMA; B-operand from live V accumulators ----------
        // wave w owns v-col tiles c = w, w+4  (h = c>>1)
        {
            __builtin_amdgcn_s_setprio(1);
            #pragma unroll
            for (int vt = 0; vt < 2; ++vt) {
                int c = w + 4*vt;
                int h = c >> 1;
                #pragma unroll
                for (int v = 0; v < 4; ++v) {
                    f32x4 pw = *(const f32x4*)(slog + ((v*4 + h)*NAG + (lc & 7))*16 + 4*rg);
                    bf16x8 a;
                    a[0]=f2bf(pw[0]); a[1]=f2bf(pw[1]); a[2]=f2bf(pw[2]); a[3]=f2bf(pw[3]);
                    a[4]=0; a[5]=0; a[6]=0; a[7]=0;
                    bf16x8 bb;
                    bb[0]=f2bf(accv[v][vt][0]); bb[1]=f2bf(accv[v][vt][1]);
                    bb[2]=f2bf(accv[v][vt][2]); bb[3]=f2bf(accv[v][vt][3]);
                    bb[4]=0; bb[5]=0; bb[6]=0; bb[7]=0;
                    f32x4 po = (f32x4){0.f,0.f,0.f,0.f};
                    po = __builtin_amdgcn_mfma_f32_16x16x32_bf16(a, bb, po, 0,0,0);
                    if (rg < 2) {
                        #pragma unroll
                        for (int r = 0; r < 4; ++r)
                            attn[(v*NAG + 4*rg + r)*X1S + c*16 + lc] = f2bf(po[r]);
                    }
                }
            }
            __builtin_amdgcn_s_setprio(0);
        }
        __syncthreads();

        // ---------- P4: attn2 = (attn @ out_w[2i+j] + b) * keep; wave w owns nt {2w,2w+1} ----------
        {
            f32x4 acc[2][2];                     // [j][n]
            #pragma unroll
            for (int j = 0; j < 2; ++j) {
                acc[j][0] = (f32x4){0.f,0.f,0.f,0.f};
                acc[j][1] = (f32x4){0.f,0.f,0.f,0.f};
            }
            __builtin_amdgcn_s_setprio(1);
            #pragma unroll
            for (int kt = 0; kt < 4; ++kt)
                #pragma unroll
                for (int j = 0; j < 2; ++j) {
                    int hyp = 2*i + j;
                    bf16x8 b0 = WF[(448 + hyp*32 + (2*w+0)*4 + kt)*64 + l];
                    bf16x8 b1 = WF[(448 + hyp*32 + (2*w+1)*4 + kt)*64 + l];
                    bf16x8 a = ld_frag(attn + (16*j + lc)*X1S + kt*32 + rg*4);
                    acc[j][0] = __builtin_amdgcn_mfma_f32_16x16x32_bf16(a, b0, acc[j][0], 0,0,0);
                    acc[j][1] = __builtin_amdgcn_mfma_f32_16x16x32_bf16(a, b1, acc[j][1], 0,0,0);
                }
            __builtin_amdgcn_s_setprio(0);
            #pragma unroll
            for (int j = 0; j < 2; ++j) {
                float bias0 = out_b[(2*i+j)*HYPD + 32*w + lc];
                float bias1 = out_b[(2*i+j)*HYPD + 32*w + 16 + lc];
                #pragma unroll
                for (int r = 0; r < 4; ++r) {
                    int lr = 4*rg + r;                       // local row: sample = lr>>3, agent = lr&7
                    float keep = 1.f - em[(lr >> 3)*NE + (lr & 7)];
                    attn2[(16*j + lr)*X1S + 32*w + lc]      = f2bf((acc[j][0][r] + bias0) * keep);
                    attn2[(16*j + lr)*X1S + 32*w + 16 + lc] = f2bf((acc[j][1][r] + bias1) * keep);
                }
            }
        }
        __syncthreads();

        // ---------- P5: outs[hyp] = (attn2 @ fc2_w[hyp] + b) * keep; wave w = (j,nt) ----------
        {
            int j = w >> 1, nt = w & 1;
            int hyp = 2*i + j;
            f32x4 acc = (f32x4){0.f,0.f,0.f,0.f};
            __builtin_amdgcn_s_setprio(1);
            #pragma unroll
            for (int kt = 0; kt < 4; ++kt) {
                bf16x8 a = ld_frag(attn2 + (16*j + lc)*X1S + kt*32 + rg*4);
                bf16x8 bfr = WF[(576 + hyp*8 + nt*4 + kt)*64 + l];
                acc = __builtin_amdgcn_mfma_f32_16x16x32_bf16(a, bfr, acc, 0,0,0);
            }
            __builtin_amdgcn_s_setprio(0);
            float bias = fc2_b[hyp*32 + nt*16 + lc];
            float vals[4];
            #pragma unroll
            for (int r = 0; r < 4; ++r) {
                int lr = 4*rg + r;                           // sample = lr>>3, agent = lr&7
                float keep = 1.f - em[(lr >> 3)*NE + (lr & 7)];
                vals[r] = (acc[r] + bias) * keep;
            }
            if (hyp == 0) {                                  // i==0, j==0 (waves 0,1)
                #pragma unroll
                for (int r = 0; r < 4; ++r)
                    out0[(4*rg + r)*32 + nt*16 + lc] = f2bf(vals[r]);
            } else {
                float ps = vals[0] + vals[1] + vals[2] + vals[3];
                ps += __shfl_xor(ps, 16);                    // pairs rg0/1 (sample 0), rg2/3 (sample 1)
                if ((rg & 1) == 0) {
                    int s = rg >> 1;
                    means[(hyp-1)*64 + s*32 + nt*16 + lc] = ps;
                }
            }
        }
        __syncthreads();
    }

    // ---------- P6: mixing (waves 0,1 = samples 0,1; lanes 0..31) ----------
    if (w < 2 && l < 32) {
        int s = w, c = l;
        float s1 = means[0*64 + s*32 + c] * 0.125f;   // mean of outs[1]
        float b1 = means[1*64 + s*32 + c] * 0.125f;   // mean of outs[2]
        float vsum = means[2*64 + s*32 + c];          // agent-sum of outs[3]

        float hid = 0.f;
        #pragma unroll
        for (int a = 0; a < NAG; ++a) {
            float x = bf2f(out0[(s*NAG + a)*32 + c]);
            float mx = x;
            #pragma unroll
            for (int m = 16; m >= 1; m >>= 1) mx = fmaxf(mx, __shfl_xor(mx, m, 32));
            float e = __expf(x - mx);
            float sum = e;
            #pragma unroll
            for (int m = 16; m >= 1; m >>= 1) sum += __shfl_xor(sum, m, 32);
            float qsv = agent_qs[(size_t)(b2 + s)*NAG + a];
            hid += qsv * (e / sum);
        }
        hid += b1;
        hid = (hid > 0.f) ? hid : expm1f(hid);

        float mx = s1;
        #pragma unroll
        for (int m = 16; m >= 1; m >>= 1) mx = fmaxf(mx, __shfl_xor(mx, m, 32));
        float e = __expf(s1 - mx);
        float ss = e;
        #pragma unroll
        for (int m = 16; m >= 1; m >>= 1) ss += __shfl_xor(ss, m, 32);
        float wf = e / ss;

        float red = hid * wf + vsum * (1.f / 256.f);
        #pragma unroll
        for (int m = 16; m >= 1; m >>= 1) red += __shfl_xor(red, m, 32);
        if (c == 0) out[b2 + s] = red;
    }
}

// ======================= fp32 fallback (verified round-1) ====================
#define QKVP 388
#define NTHR 384
__device__ __forceinline__ float4 f4load(const float* p) { return *reinterpret_cast<const float4*>(p); }
__device__ __forceinline__ void f4store(float* p, const float4& v) { *reinterpret_cast<float4*>(p) = v; }
__device__ __forceinline__ void f4fma(float4& a, float s, const float4& w) {
    a.x += s * w.x; a.y += s * w.y; a.z += s * w.z; a.w += s * w.w;
}

__global__ __launch_bounds__(NTHR) void flexq_fp32(
    const float* __restrict__ agent_qs, const float* __restrict__ entities,
    const int* __restrict__ entity_mask, const float* __restrict__ fc1_w,
    const float* __restrict__ fc1_b, const float* __restrict__ attn_w,
    const float* __restrict__ out_w, const float* __restrict__ out_b,
    const float* __restrict__ fc2_w, const float* __restrict__ fc2_b,
    float* __restrict__ out)
{
    const int b = blockIdx.x, tid = threadIdx.x;
    __shared__ float s_ent[NE][ED];
    __shared__ float s_x1t[HYPD][NE];
    __shared__ float s_qkv[NE][QKVP];
    __shared__ float s_w[4][NAG][NE];
    __shared__ float s_attn[NAG][HYPD];
    __shared__ float s_attnout[NAG][HYPD];
    __shared__ float s_outs[4][NAG][32];
    __shared__ float s_mask[NE];
    __shared__ float s_qs[NAG];

    const float* ent = entities + (size_t)b * NE * ED;
    for (int o = tid; o < NE * ED; o += NTHR) s_ent[o >> 6][o & 63] = ent[o];
    if (tid < NE) s_mask[tid] = (entity_mask[(size_t)b * NE + tid] != 0) ? 1.0f : 0.0f;
    if (tid < NAG) s_qs[tid] = agent_qs[(size_t)b * NAG + tid];
    __syncthreads();

    for (int i = 0; i < 4; ++i) {
        {
            const float* W1 = fc1_w + i * ED * HYPD;
            const float* B1 = fc1_b + i * HYPD;
            for (int o4 = tid; o4 < 512; o4 += NTHR) {
                int e = o4 >> 5, j = (o4 & 31) * 4;
                float4 acc = f4load(B1 + j);
                for (int d = 0; d < ED; ++d) { float x = s_ent[e][d]; f4fma(acc, x, f4load(W1 + d * HYPD + j)); }
                s_x1t[j+0][e] = fmaxf(acc.x, 0.f); s_x1t[j+1][e] = fmaxf(acc.y, 0.f);
                s_x1t[j+2][e] = fmaxf(acc.z, 0.f); s_x1t[j+3][e] = fmaxf(acc.w, 0.f);
            }
        }
        __syncthreads();
        {
            const float* W2 = attn_w + i * HYPD * QKVW;
            int j = (tid % 96) * 4, e0 = (tid / 96) * 4;
            float4 a0 = {0,0,0,0}, a1 = {0,0,0,0}, a2 = {0,0,0,0}, a3 = {0,0,0,0};
            for (int d = 0; d < HYPD; ++d) {
                float4 wv = f4load(W2 + d * QKVW + j);
                float4 x = f4load(&s_x1t[d][e0]);
                f4fma(a0, x.x, wv); f4fma(a1, x.y, wv); f4fma(a2, x.z, wv); f4fma(a3, x.w, wv);
            }
            f4store(&s_qkv[e0+0][j], a0); f4store(&s_qkv[e0+1][j], a1);
            f4store(&s_qkv[e0+2][j], a2); f4store(&s_qkv[e0+3][j], a3);
        }
        __syncthreads();
        {
            const float inv_scale = 0.17677669529663687f;
            for (int o = tid; o < 512; o += NTHR) {
                int h = o >> 7, qi = (o >> 4) & 7, kk = o & 15;
                const float* qp = &s_qkv[qi][h * 32];
                const float* kp = &s_qkv[kk][HYPD + h * 32];
                float s = 0.f;
                #pragma unroll
                for (int d4 = 0; d4 < 8; ++d4) {
                    float4 qv = f4load(qp + 4 * d4), kv2 = f4load(kp + 4 * d4);
                    s += qv.x*kv2.x + qv.y*kv2.y + qv.z*kv2.z + qv.w*kv2.w;
                }
                s_w[h][qi][kk] = s * inv_scale;
            }
        }
        __syncthreads();
        if (tid < 32) {
            int h = tid >> 3, qi = tid & 7;
            float am = s_mask[qi];
            float mx = -3.0e38f; bool any = false;
            #pragma unroll
            for (int kk = 0; kk < NE; ++kk)
                if (s_mask[kk] == 0.f) { any = true; mx = fmaxf(mx, s_w[h][qi][kk]); }
            if (am != 0.f || !any) {
                #pragma unroll
                for (int kk = 0; kk < NE; ++kk) s_w[h][qi][kk] = 0.f;
            } else {
                float eb[NE]; float sum = 0.f;
                #pragma unroll
                for (int kk = 0; kk < NE; ++kk) {
                    float e = (s_mask[kk] == 0.f) ? __expf(s_w[h][qi][kk] - mx) : 0.f;
                    eb[kk] = e; sum += e;
                }
                float inv = 1.f / sum;
                #pragma unroll
                for (int kk = 0; kk < NE; ++kk) s_w[h][qi][kk] = eb[kk] * inv;
            }
        }
        __syncthreads();
        if (tid < 256) {
            int qi = tid >> 5, j = (tid & 31) * 4, h = j >> 5, d0 = j & 31;
            float4 acc = {0,0,0,0};
            #pragma unroll
            for (int kk = 0; kk < NE; ++kk) f4fma(acc, s_w[h][qi][kk], f4load(&s_qkv[kk][2*HYPD + h*32 + d0]));
            f4store(&s_attn[qi][j], acc);
        }
        __syncthreads();
        if (tid < 256) {
            const float* W3 = out_w + i * HYPD * HYPD;
            const float* B3 = out_b + i * HYPD;
            int qi = tid >> 5, j = (tid & 31) * 4;
            float4 acc = f4load(B3 + j);
            for (int d = 0; d < HYPD; ++d) f4fma(acc, s_attn[qi][d], f4load(W3 + d * HYPD + j));
            float keep = 1.f - s_mask[qi];
            acc.x *= keep; acc.y *= keep; acc.z *= keep; acc.w *= keep;
            f4store(&s_attnout[qi][j], acc);
        }
        __syncthreads();
        if (tid < 64) {
            const float* W4 = fc2_w + i * HYPD * 32;
            const float* B4 = fc2_b + i * 32;
            int qi = tid >> 3, c = (tid & 7) * 4;
            float4 acc = f4load(B4 + c);
            for (int d = 0; d < HYPD; ++d) f4fma(acc, s_attnout[qi][d], f4load(W4 + d * 32 + c));
            float keep = 1.f - s_mask[qi];
            acc.x *= keep; acc.y *= keep; acc.z *= keep; acc.w *= keep;
            f4store(&s_outs[i][qi][c], acc);
        }
        __syncthreads();
    }

    if (tid < 32) {
        const int c = tid;
        float b1 = 0.f, s1 = 0.f, vs = 0.f;
        #pragma unroll
        for (int qi = 0; qi < NAG; ++qi) {
            b1 += s_outs[2][qi][c]; s1 += s_outs[1][qi][c]; vs += s_outs[3][qi][c];
        }
        b1 *= 0.125f; s1 *= 0.125f;
        float hid = 0.f;
        #pragma unroll
        for (int a = 0; a < NAG; ++a) {
            float x = s_outs[0][a][c];
            float mx = x;
            #pragma unroll
            for (int m = 16; m >= 1; m >>= 1) mx = fmaxf(mx, __shfl_xor(mx, m, 32));
            float e = __expf(x - mx);
            float sm = e;
            #pragma unroll
            for (int m = 16; m >= 1; m >>= 1) sm += __shfl_xor(sm, m, 32);
            hid += s_qs[a] * (e / sm);
        }
        hid += b1;
        hid = (hid > 0.f) ? hid : expm1f(hid);
        float mx = s1;
        #pragma unroll
        for (int m = 16; m >= 1; m >>= 1) mx = fmaxf(mx, __shfl_xor(mx, m, 32));
        float e = __expf(s1 - mx);
        float ssum = e;
        #pragma unroll
        for (int m = 16; m >= 1; m >>= 1) ssum += __shfl_xor(ssum, m, 32);
        float wf = e / ssum;
        float red = hid * wf + vs * (1.f / 256.f);
        #pragma unroll
        for (int m = 16; m >= 1; m >>= 1) red += __shfl_xor(red, m, 32);
        if (tid == 0) out[b] = red;
    }
}

extern "C" void kernel_launch(void* const* d_in, const int* in_sizes, int n_in,
                              void* d_out, int out_size, void* d_ws, size_t ws_size,
                              hipStream_t stream) {
    const float* agent_qs    = (const float*)d_in[0];
    const float* entities    = (const float*)d_in[1];
    const int*   entity_mask = (const int*)  d_in[2];
    const float* fc1_w       = (const float*)d_in[3];
    const float* fc1_b       = (const float*)d_in[4];
    const float* attn_w      = (const float*)d_in[5];
    const float* out_w       = (const float*)d_in[6];
    const float* out_b       = (const float*)d_in[7];
    const float* fc2_w       = (const float*)d_in[8];
    const float* fc2_b       = (const float*)d_in[9];
    float* out = (float*)d_out;

    const int B = in_sizes[0] / NAG;  // 8192

    if (ws_size >= (size_t)(608 * 1024) && (B % SB) == 0) {
        pack_weights<<<152, 256, 0, stream>>>(fc1_w, attn_w, out_w, fc2_w, (short*)d_ws);
        flexq_mfma<<<B / SB, 256, 0, stream>>>(agent_qs, entities, entity_mask,
                                               fc1_b, out_b, fc2_b,
                                               (const short*)d_ws, out, B);
    } else {
        flexq_fp32<<<B, NTHR, 0, stream>>>(agent_qs, entities, entity_mask,
                                           fc1_w, fc1_b, attn_w, out_w, out_b,
                                           fc2_w, fc2_b, out);
    }
}

// Round 14
// 186.541 us; speedup vs baseline: 1.1860x; 1.1860x over previous
//
#include <hip/hip_runtime.h>
#include <math.h>

#define NAG 8
#define NE  16
#define ED  64
#define HYPD 128
#define QKVW 384
#define SB 4

#define X1S 132
#define KS  132
#define QS  132

// LDS layout (bytes):
//  x1    @ 0     : 64*132*2 = 16896  (overlays: slog f32[2048] @0..8192, attn[32][132] @8448..16896)
//  k     @ 16896 : 64*132*2 = 16896  (attn2[32][132] overlays @16896; k dead after P3a)
//  q     @ 33792 : 32*132*2 = 8448
//  out0  @ 42240 : 32*32*2  = 2048
//  means @ 44288 : 3*4*32*4 = 1536
//  em    @ 45824 : 64*4     = 256
#define OFF_X1    0
#define OFF_SLOG  0
#define OFF_ATTN  8448
#define OFF_K     16896
#define OFF_ATTN2 16896
#define OFF_Q     33792
#define OFF_OUT0  42240
#define OFF_MEANS 44288
#define OFF_EM    45824
#define LDS_BYTES 46080

typedef __attribute__((ext_vector_type(8))) short bf16x8;
typedef __attribute__((ext_vector_type(4))) short bf16x4;
typedef __attribute__((ext_vector_type(4))) float f32x4;

__device__ __forceinline__ short f2bf(float f) {
    union { float f; unsigned u; } c; c.f = f;
    unsigned r = (c.u + 0x7FFFu + ((c.u >> 16) & 1u)) >> 16;
    return (short)r;
}
__device__ __forceinline__ float bf2f(short s) {
    union { unsigned u; float f; } c; c.u = ((unsigned)(unsigned short)s) << 16; return c.f;
}
__device__ __forceinline__ bf16x8 ld_frag(const short* p) {
    bf16x4 lo = *(const bf16x4*)p;
    bf16x4 hi = *(const bf16x4*)(p + 16);
    return __builtin_shufflevector(lo, hi, 0, 1, 2, 3, 4, 5, 6, 7);
}

// ---------------- weight packing: fp32 -> bf16 MFMA B-fragments -------------
// slot map: fc1 [0,64) = h*16+nt*2+kt ; attn [64,448) = 64+h*96+nt*4+kt ;
//           out [448,576) = 448+h*32+nt*4+kt ; fc2 [576,608) = 576+h*8+nt*4+kt
// frag elem j of lane l: k = kt*32 + 4*(l>>4) + (j&3) + 16*(j>>2), n = nt*16 + (l&15)
__global__ void pack_weights(const float* __restrict__ fc1_w,
                             const float* __restrict__ attn_w,
                             const float* __restrict__ out_w,
                             const float* __restrict__ fc2_w,
                             short* __restrict__ ws) {
    int gid = blockIdx.x * 256 + threadIdx.x;
    if (gid >= 608 * 64) return;
    int slot = gid >> 6, l = gid & 63;
    const float* src; int N, nt, kt;
    if (slot < 64) {
        int h = slot >> 4, f = slot & 15;
        nt = f >> 1; kt = f & 1; N = HYPD; src = fc1_w + h * ED * HYPD;
    } else if (slot < 448) {
        int s2 = slot - 64; int h = s2 / 96, f = s2 % 96;
        nt = f >> 2; kt = f & 3; N = QKVW; src = attn_w + h * HYPD * QKVW;
    } else if (slot < 576) {
        int s2 = slot - 448; int h = s2 >> 5, f = s2 & 31;
        nt = f >> 2; kt = f & 3; N = HYPD; src = out_w + h * HYPD * HYPD;
    } else {
        int s2 = slot - 576; int h = s2 >> 3, f = s2 & 7;
        nt = f >> 2; kt = f & 3; N = 32; src = fc2_w + h * HYPD * 32;
    }
    int rg = l >> 4, lc = l & 15;
    bf16x8 fr;
    #pragma unroll
    for (int j = 0; j < 8; ++j) {
        int k = kt * 32 + 4 * rg + (j & 3) + 16 * (j >> 2);
        fr[j] = f2bf(src[k * N + nt * 16 + lc]);
    }
    ((bf16x8*)ws)[slot * 64 + l] = fr;
}

// ---------------- fused MFMA kernel: 4 samples / block, 256 threads ---------
__global__ __launch_bounds__(256, 2) void flexq_mfma(
    const float* __restrict__ agent_qs,
    const float* __restrict__ entities,
    const int*   __restrict__ entity_mask,
    const float* __restrict__ fc1_b,
    const float* __restrict__ out_b,
    const float* __restrict__ fc2_b,
    const short* __restrict__ wfrag,
    float* __restrict__ out, int B)
{
    __shared__ __align__(16) char smem[LDS_BYTES];
    short* x1    = (short*)(smem + OFF_X1);
    float* slog  = (float*)(smem + OFF_SLOG);
    short* attn  = (short*)(smem + OFF_ATTN);
    short* k     = (short*)(smem + OFF_K);
    short* attn2 = (short*)(smem + OFF_ATTN2);
    short* q     = (short*)(smem + OFF_Q);
    short* out0  = (short*)(smem + OFF_OUT0);
    float* means = (float*)(smem + OFF_MEANS);
    float* em    = (float*)(smem + OFF_EM);

    const int tid = threadIdx.x;
    const int l = tid & 63, w = tid >> 6;        // 4 waves
    const int rg = l >> 4, lc = l & 15;
    const int b4 = blockIdx.x * SB;
    const bf16x8* WF = (const bf16x8*)wfrag;

    if (tid < 64)
        em[tid] = (entity_mask[(size_t)b4 * NE + tid] != 0) ? 1.0f : 0.0f;

    // entity A-fragments converted once, held in registers across all 4 hyps
    bf16x8 aent[2][4];
    #pragma unroll
    for (int kt = 0; kt < 2; ++kt)
        #pragma unroll
        for (int mt = 0; mt < 4; ++mt) {
            const float* ap = entities + ((size_t)(b4 + mt) * NE + lc) * ED + kt * 32 + rg * 4;
            float4 lo = *(const float4*)ap;
            float4 hi = *(const float4*)(ap + 16);
            bf16x8 af;
            af[0]=f2bf(lo.x); af[1]=f2bf(lo.y); af[2]=f2bf(lo.z); af[3]=f2bf(lo.w);
            af[4]=f2bf(hi.x); af[5]=f2bf(hi.y); af[6]=f2bf(hi.z); af[7]=f2bf(hi.w);
            aent[kt][mt] = af;
        }
    __syncthreads();

    for (int i = 0; i < 4; ++i) {
        // ---------- P1: x1 = relu(ent @ fc1_w + fc1_b); wave w owns nt {2w,2w+1} ----------
        {
            f32x4 acc[4][2];
            #pragma unroll
            for (int mt = 0; mt < 4; ++mt) {
                acc[mt][0] = (f32x4){0.f,0.f,0.f,0.f};
                acc[mt][1] = (f32x4){0.f,0.f,0.f,0.f};
            }
            #pragma unroll
            for (int kt = 0; kt < 2; ++kt) {
                bf16x8 b0 = WF[(i*16 + (2*w+0)*2 + kt)*64 + l];
                bf16x8 b1 = WF[(i*16 + (2*w+1)*2 + kt)*64 + l];
                #pragma unroll
                for (int mt = 0; mt < 4; ++mt) {
                    acc[mt][0] = __builtin_amdgcn_mfma_f32_16x16x32_bf16(aent[kt][mt], b0, acc[mt][0], 0,0,0);
                    acc[mt][1] = __builtin_amdgcn_mfma_f32_16x16x32_bf16(aent[kt][mt], b1, acc[mt][1], 0,0,0);
                }
            }
            float bias0 = fc1_b[i*HYPD + 32*w + lc];
            float bias1 = fc1_b[i*HYPD + 32*w + 16 + lc];
            #pragma unroll
            for (int mt = 0; mt < 4; ++mt)
                #pragma unroll
                for (int r = 0; r < 4; ++r) {
                    int row = 16*mt + 4*rg + r;
                    x1[row*X1S + 32*w + lc]      = f2bf(fmaxf(acc[mt][0][r] + bias0, 0.f));
                    x1[row*X1S + 32*w + 16 + lc] = f2bf(fmaxf(acc[mt][1][r] + bias1, 0.f));
                }
        }
        __syncthreads();

        // ---------- P2: qkv = x1 @ attn_w; interleaved nt; V stays in registers ----------
        f32x4 accv[4][2];   // V-tile accumulators (nt = w+16, w+20), live through P3
        // half 1: nt {w, w+4, w+8}  (q, q, k)
        {
            f32x4 acc[4][3];
            #pragma unroll
            for (int mt = 0; mt < 4; ++mt)
                #pragma unroll
                for (int n = 0; n < 3; ++n) acc[mt][n] = (f32x4){0.f,0.f,0.f,0.f};
            #pragma unroll
            for (int kt = 0; kt < 4; ++kt) {
                bf16x8 b0 = WF[(64 + i*96 + (w +  0)*4 + kt)*64 + l];
                bf16x8 b1 = WF[(64 + i*96 + (w +  4)*4 + kt)*64 + l];
                bf16x8 b2 = WF[(64 + i*96 + (w +  8)*4 + kt)*64 + l];
                #pragma unroll
                for (int mt = 0; mt < 4; ++mt) {
                    bf16x8 a = ld_frag(x1 + (16*mt + lc)*X1S + kt*32 + rg*4);
                    acc[mt][0] = __builtin_amdgcn_mfma_f32_16x16x32_bf16(a, b0, acc[mt][0], 0,0,0);
                    acc[mt][1] = __builtin_amdgcn_mfma_f32_16x16x32_bf16(a, b1, acc[mt][1], 0,0,0);
                    acc[mt][2] = __builtin_amdgcn_mfma_f32_16x16x32_bf16(a, b2, acc[mt][2], 0,0,0);
                }
            }
            #pragma unroll
            for (int mt = 0; mt < 4; ++mt)
                #pragma unroll
                for (int r = 0; r < 4; ++r) {
                    if (rg < 2) {   // q tiles: agent rows only
                        q[(mt*NAG + 4*rg + r)*QS + (w+0)*16 + lc] = f2bf(acc[mt][0][r]);
                        q[(mt*NAG + 4*rg + r)*QS + (w+4)*16 + lc] = f2bf(acc[mt][1][r]);
                    }
                    k[(16*mt + 4*rg + r)*KS + w*16 + lc] = f2bf(acc[mt][2][r]);   // nt=w+8 -> kcol w
                }
        }
        // half 2: nt {w+12, w+16, w+20}  (k, v, v)
        {
            f32x4 acck[4];
            #pragma unroll
            for (int mt = 0; mt < 4; ++mt) {
                acck[mt] = (f32x4){0.f,0.f,0.f,0.f};
                accv[mt][0] = (f32x4){0.f,0.f,0.f,0.f};
                accv[mt][1] = (f32x4){0.f,0.f,0.f,0.f};
            }
            #pragma unroll
            for (int kt = 0; kt < 4; ++kt) {
                bf16x8 b0 = WF[(64 + i*96 + (w + 12)*4 + kt)*64 + l];
                bf16x8 b1 = WF[(64 + i*96 + (w + 16)*4 + kt)*64 + l];
                bf16x8 b2 = WF[(64 + i*96 + (w + 20)*4 + kt)*64 + l];
                #pragma unroll
                for (int mt = 0; mt < 4; ++mt) {
                    bf16x8 a = ld_frag(x1 + (16*mt + lc)*X1S + kt*32 + rg*4);
                    acck[mt]    = __builtin_amdgcn_mfma_f32_16x16x32_bf16(a, b0, acck[mt], 0,0,0);
                    accv[mt][0] = __builtin_amdgcn_mfma_f32_16x16x32_bf16(a, b1, accv[mt][0], 0,0,0);
                    accv[mt][1] = __builtin_amdgcn_mfma_f32_16x16x32_bf16(a, b2, accv[mt][1], 0,0,0);
                }
            }
            #pragma unroll
            for (int mt = 0; mt < 4; ++mt)
                #pragma unroll
                for (int r = 0; r < 4; ++r)
                    k[(16*mt + 4*rg + r)*KS + (w+4)*16 + lc] = f2bf(acck[mt][r]);  // nt=w+12 -> kcol w+4
        }
        __syncthreads();

        // ---------- P3a: logits via MFMA (store scaled logits) ----------
        {
            #pragma unroll
            for (int pp = 0; pp < 4; ++pp) {
                int p = 4*w + pp, s = p >> 2, h = p & 3;
                bf16x8 a  = ld_frag(q + (s*NAG + (lc & 7))*QS + h*32 + rg*4);
                bf16x8 bb = ld_frag(k + (s*NE  + lc)*KS       + h*32 + rg*4);
                f32x4 acc = (f32x4){0.f,0.f,0.f,0.f};
                acc = __builtin_amdgcn_mfma_f32_16x16x32_bf16(a, bb, acc, 0,0,0);
                if (rg < 2) {
                    #pragma unroll
                    for (int r = 0; r < 4; ++r)
                        slog[((s*4 + h)*NAG + 4*rg + r)*16 + lc] = acc[r] * 0.17677669529663687f;
                }
            }
        }
        __syncthreads();

        // ---------- P3b: masked softmax (verified serial path, 128 rows) ----------
        if (tid < 128) {
            int s = tid >> 5, h = (tid >> 3) & 3, qi = tid & 7;
            float am = em[s*NE + qi];
            float* rowp = slog + ((s*4 + h)*NAG + qi)*16;
            float mx = -3.0e38f; bool any = false;
            #pragma unroll
            for (int kk = 0; kk < NE; ++kk)
                if (em[s*NE + kk] == 0.f) { any = true; mx = fmaxf(mx, rowp[kk]); }
            if (am != 0.f || !any) {
                #pragma unroll
                for (int kk = 0; kk < NE; ++kk) rowp[kk] = 0.f;
            } else {
                float eb[NE]; float sum = 0.f;
                #pragma unroll
                for (int kk = 0; kk < NE; ++kk) {
                    float e = (em[s*NE + kk] == 0.f) ? __expf(rowp[kk] - mx) : 0.f;
                    eb[kk] = e; sum += e;
                }
                float inv = 1.f / sum;
                #pragma unroll
                for (int kk = 0; kk < NE; ++kk) rowp[kk] = eb[kk] * inv;
            }
        }
        __syncthreads();

        // ---------- P3c: PV via MFMA; B-operand from live V accumulators ----------
        // wave w owns v-col tiles c = w, w+4  (h = c>>1)
        {
            #pragma unroll
            for (int vt = 0; vt < 2; ++vt) {
                int c = w + 4*vt;
                int h = c >> 1;
                #pragma unroll
                for (int mt = 0; mt < 4; ++mt) {
                    f32x4 pw = *(const f32x4*)(slog + ((mt*4 + h)*NAG + (lc & 7))*16 + 4*rg);
                    bf16x8 a;
                    a[0]=f2bf(pw[0]); a[1]=f2bf(pw[1]); a[2]=f2bf(pw[2]); a[3]=f2bf(pw[3]);
                    a[4]=0; a[5]=0; a[6]=0; a[7]=0;
                    bf16x8 bb;
                    bb[0]=f2bf(accv[mt][vt][0]); bb[1]=f2bf(accv[mt][vt][1]);
                    bb[2]=f2bf(accv[mt][vt][2]); bb[3]=f2bf(accv[mt][vt][3]);
                    bb[4]=0; bb[5]=0; bb[6]=0; bb[7]=0;
                    f32x4 po = (f32x4){0.f,0.f,0.f,0.f};
                    po = __builtin_amdgcn_mfma_f32_16x16x32_bf16(a, bb, po, 0,0,0);
                    if (rg < 2) {
                        #pragma unroll
                        for (int r = 0; r < 4; ++r)
                            attn[(mt*NAG + 4*rg + r)*X1S + c*16 + lc] = f2bf(po[r]);
                    }
                }
            }
        }
        __syncthreads();

        // ---------- P4: attn2 = (attn @ out_w + out_b) * keep; wave w owns nt {2w,2w+1} ----------
        {
            f32x4 acc[2][2];
            #pragma unroll
            for (int mt = 0; mt < 2; ++mt) {
                acc[mt][0] = (f32x4){0.f,0.f,0.f,0.f};
                acc[mt][1] = (f32x4){0.f,0.f,0.f,0.f};
            }
            #pragma unroll
            for (int kt = 0; kt < 4; ++kt) {
                bf16x8 b0 = WF[(448 + i*32 + (2*w+0)*4 + kt)*64 + l];
                bf16x8 b1 = WF[(448 + i*32 + (2*w+1)*4 + kt)*64 + l];
                #pragma unroll
                for (int mt = 0; mt < 2; ++mt) {
                    bf16x8 a = ld_frag(attn + (16*mt + lc)*X1S + kt*32 + rg*4);
                    acc[mt][0] = __builtin_amdgcn_mfma_f32_16x16x32_bf16(a, b0, acc[mt][0], 0,0,0);
                    acc[mt][1] = __builtin_amdgcn_mfma_f32_16x16x32_bf16(a, b1, acc[mt][1], 0,0,0);
                }
            }
            float bias0 = out_b[i*HYPD + 32*w + lc];
            float bias1 = out_b[i*HYPD + 32*w + 16 + lc];
            #pragma unroll
            for (int mt = 0; mt < 2; ++mt)
                #pragma unroll
                for (int r = 0; r < 4; ++r) {
                    int row = 16*mt + 4*rg + r;
                    float keep = 1.f - em[(row >> 3)*NE + (row & 7)];
                    attn2[row*X1S + 32*w + lc]      = f2bf((acc[mt][0][r] + bias0) * keep);
                    attn2[row*X1S + 32*w + 16 + lc] = f2bf((acc[mt][1][r] + bias1) * keep);
                }
        }
        __syncthreads();

        // ---------- P5: outs[i] = (attn2 @ fc2_w + fc2_b) * keep; wave w = (mt,nt) ----------
        {
            int mt = w >> 1, nt = w & 1;
            f32x4 acc = (f32x4){0.f,0.f,0.f,0.f};
            #pragma unroll
            for (int kt = 0; kt < 4; ++kt) {
                bf16x8 a = ld_frag(attn2 + (16*mt + lc)*X1S + kt*32 + rg*4);
                bf16x8 bfr = WF[(576 + i*8 + nt*4 + kt)*64 + l];
                acc = __builtin_amdgcn_mfma_f32_16x16x32_bf16(a, bfr, acc, 0,0,0);
            }
            float bias = fc2_b[i*32 + nt*16 + lc];
            float vals[4];
            #pragma unroll
            for (int r = 0; r < 4; ++r) {
                int row = 16*mt + 4*rg + r;
                float keep = 1.f - em[(row >> 3)*NE + (row & 7)];
                vals[r] = (acc[r] + bias) * keep;
            }
            if (i == 0) {
                #pragma unroll
                for (int r = 0; r < 4; ++r)
                    out0[(16*mt + 4*rg + r)*32 + nt*16 + lc] = f2bf(vals[r]);
            } else {
                float ps = vals[0] + vals[1] + vals[2] + vals[3];
                ps += __shfl_xor(ps, 16);
                if ((rg & 1) == 0) {
                    int s = 2*mt + (rg >> 1);
                    means[(i-1)*128 + s*32 + nt*16 + lc] = ps;
                }
            }
        }
        __syncthreads();
    }

    // ---------- P6: mixing (wave w = sample w, lanes 0..31) ----------
    if (l < 32) {
        int s = w, c = l;
        float s1 = means[0*128 + s*32 + c] * 0.125f;   // mean of outs[1]
        float b1 = means[1*128 + s*32 + c] * 0.125f;   // mean of outs[2]
        float vsum = means[2*128 + s*32 + c];          // agent-sum of outs[3]

        float hid = 0.f;
        #pragma unroll
        for (int a = 0; a < NAG; ++a) {
            float x = bf2f(out0[(s*NAG + a)*32 + c]);
            float mx = x;
            #pragma unroll
            for (int m = 16; m >= 1; m >>= 1) mx = fmaxf(mx, __shfl_xor(mx, m, 32));
            float e = __expf(x - mx);
            float sum = e;
            #pragma unroll
            for (int m = 16; m >= 1; m >>= 1) sum += __shfl_xor(sum, m, 32);
            float qsv = agent_qs[(size_t)(b4 + s)*NAG + a];
            hid += qsv * (e / sum);
        }
        hid += b1;
        hid = (hid > 0.f) ? hid : expm1f(hid);

        float mx = s1;
        #pragma unroll
        for (int m = 16; m >= 1; m >>= 1) mx = fmaxf(mx, __shfl_xor(mx, m, 32));
        float e = __expf(s1 - mx);
        float ss = e;
        #pragma unroll
        for (int m = 16; m >= 1; m >>= 1) ss += __shfl_xor(ss, m, 32);
        float wf = e / ss;

        float red = hid * wf + vsum * (1.f / 256.f);
        #pragma unroll
        for (int m = 16; m >= 1; m >>= 1) red += __shfl_xor(red, m, 32);
        if (c == 0) out[b4 + s] = red;
    }
}

// ======================= fp32 fallback (verified round-1) ====================
#define QKVP 388
#define NTHR 384
__device__ __forceinline__ float4 f4load(const float* p) { return *reinterpret_cast<const float4*>(p); }
__device__ __forceinline__ void f4store(float* p, const float4& v) { *reinterpret_cast<float4*>(p) = v; }
__device__ __forceinline__ void f4fma(float4& a, float s, const float4& w) {
    a.x += s * w.x; a.y += s * w.y; a.z += s * w.z; a.w += s * w.w;
}

__global__ __launch_bounds__(NTHR) void flexq_fp32(
    const float* __restrict__ agent_qs, const float* __restrict__ entities,
    const int* __restrict__ entity_mask, const float* __restrict__ fc1_w,
    const float* __restrict__ fc1_b, const float* __restrict__ attn_w,
    const float* __restrict__ out_w, const float* __restrict__ out_b,
    const float* __restrict__ fc2_w, const float* __restrict__ fc2_b,
    float* __restrict__ out)
{
    const int b = blockIdx.x, tid = threadIdx.x;
    __shared__ float s_ent[NE][ED];
    __shared__ float s_x1t[HYPD][NE];
    __shared__ float s_qkv[NE][QKVP];
    __shared__ float s_w[4][NAG][NE];
    __shared__ float s_attn[NAG][HYPD];
    __shared__ float s_attnout[NAG][HYPD];
    __shared__ float s_outs[4][NAG][32];
    __shared__ float s_mask[NE];
    __shared__ float s_qs[NAG];

    const float* ent = entities + (size_t)b * NE * ED;
    for (int o = tid; o < NE * ED; o += NTHR) s_ent[o >> 6][o & 63] = ent[o];
    if (tid < NE) s_mask[tid] = (entity_mask[(size_t)b * NE + tid] != 0) ? 1.0f : 0.0f;
    if (tid < NAG) s_qs[tid] = agent_qs[(size_t)b * NAG + tid];
    __syncthreads();

    for (int i = 0; i < 4; ++i) {
        {
            const float* W1 = fc1_w + i * ED * HYPD;
            const float* B1 = fc1_b + i * HYPD;
            for (int o4 = tid; o4 < 512; o4 += NTHR) {
                int e = o4 >> 5, j = (o4 & 31) * 4;
                float4 acc = f4load(B1 + j);
                for (int d = 0; d < ED; ++d) { float x = s_ent[e][d]; f4fma(acc, x, f4load(W1 + d * HYPD + j)); }
                s_x1t[j+0][e] = fmaxf(acc.x, 0.f); s_x1t[j+1][e] = fmaxf(acc.y, 0.f);
                s_x1t[j+2][e] = fmaxf(acc.z, 0.f); s_x1t[j+3][e] = fmaxf(acc.w, 0.f);
            }
        }
        __syncthreads();
        {
            const float* W2 = attn_w + i * HYPD * QKVW;
            int j = (tid % 96) * 4, e0 = (tid / 96) * 4;
            float4 a0 = {0,0,0,0}, a1 = {0,0,0,0}, a2 = {0,0,0,0}, a3 = {0,0,0,0};
            for (int d = 0; d < HYPD; ++d) {
                float4 wv = f4load(W2 + d * QKVW + j);
                float4 x = f4load(&s_x1t[d][e0]);
                f4fma(a0, x.x, wv); f4fma(a1, x.y, wv); f4fma(a2, x.z, wv); f4fma(a3, x.w, wv);
            }
            f4store(&s_qkv[e0+0][j], a0); f4store(&s_qkv[e0+1][j], a1);
            f4store(&s_qkv[e0+2][j], a2); f4store(&s_qkv[e0+3][j], a3);
        }
        __syncthreads();
        {
            const float inv_scale = 0.17677669529663687f;
            for (int o = tid; o < 512; o += NTHR) {
                int h = o >> 7, qi = (o >> 4) & 7, kk = o & 15;
                const float* qp = &s_qkv[qi][h * 32];
                const float* kp = &s_qkv[kk][HYPD + h * 32];
                float s = 0.f;
                #pragma unroll
                for (int d4 = 0; d4 < 8; ++d4) {
                    float4 qv = f4load(qp + 4 * d4), kv2 = f4load(kp + 4 * d4);
                    s += qv.x*kv2.x + qv.y*kv2.y + qv.z*kv2.z + qv.w*kv2.w;
                }
                s_w[h][qi][kk] = s * inv_scale;
            }
        }
        __syncthreads();
        if (tid < 32) {
            int h = tid >> 3, qi = tid & 7;
            float am = s_mask[qi];
            float mx = -3.0e38f; bool any = false;
            #pragma unroll
            for (int kk = 0; kk < NE; ++kk)
                if (s_mask[kk] == 0.f) { any = true; mx = fmaxf(mx, s_w[h][qi][kk]); }
            if (am != 0.f || !any) {
                #pragma unroll
                for (int kk = 0; kk < NE; ++kk) s_w[h][qi][kk] = 0.f;
            } else {
                float eb[NE]; float sum = 0.f;
                #pragma unroll
                for (int kk = 0; kk < NE; ++kk) {
                    float e = (s_mask[kk] == 0.f) ? __expf(s_w[h][qi][kk] - mx) : 0.f;
                    eb[kk] = e; sum += e;
                }
                float inv = 1.f / sum;
                #pragma unroll
                for (int kk = 0; kk < NE; ++kk) s_w[h][qi][kk] = eb[kk] * inv;
            }
        }
        __syncthreads();
        if (tid < 256) {
            int qi = tid >> 5, j = (tid & 31) * 4, h = j >> 5, d0 = j & 31;
            float4 acc = {0,0,0,0};
            #pragma unroll
            for (int kk = 0; kk < NE; ++kk) f4fma(acc, s_w[h][qi][kk], f4load(&s_qkv[kk][2*HYPD + h*32 + d0]));
            f4store(&s_attn[qi][j], acc);
        }
        __syncthreads();
        if (tid < 256) {
            const float* W3 = out_w + i * HYPD * HYPD;
            const float* B3 = out_b + i * HYPD;
            int qi = tid >> 5, j = (tid & 31) * 4;
            float4 acc = f4load(B3 + j);
            for (int d = 0; d < HYPD; ++d) f4fma(acc, s_attn[qi][d], f4load(W3 + d * HYPD + j));
            float keep = 1.f - s_mask[qi];
            acc.x *= keep; acc.y *= keep; acc.z *= keep; acc.w *= keep;
            f4store(&s_attnout[qi][j], acc);
        }
        __syncthreads();
        if (tid < 64) {
            const float* W4 = fc2_w + i * HYPD * 32;
            const float* B4 = fc2_b + i * 32;
            int qi = tid >> 3, c = (tid & 7) * 4;
            float4 acc = f4load(B4 + c);
            for (int d = 0; d < HYPD; ++d) f4fma(acc, s_attnout[qi][d], f4load(W4 + d * 32 + c));
            float keep = 1.f - s_mask[qi];
            acc.x *= keep; acc.y *= keep; acc.z *= keep; acc.w *= keep;
            f4store(&s_outs[i][qi][c], acc);
        }
        __syncthreads();
    }

    if (tid < 32) {
        const int c = tid;
        float b1 = 0.f, s1 = 0.f, vs = 0.f;
        #pragma unroll
        for (int qi = 0; qi < NAG; ++qi) {
            b1 += s_outs[2][qi][c]; s1 += s_outs[1][qi][c]; vs += s_outs[3][qi][c];
        }
        b1 *= 0.125f; s1 *= 0.125f;
        float hid = 0.f;
        #pragma unroll
        for (int a = 0; a < NAG; ++a) {
            float x = s_outs[0][a][c];
            float mx = x;
            #pragma unroll
            for (int m = 16; m >= 1; m >>= 1) mx = fmaxf(mx, __shfl_xor(mx, m, 32));
            float e = __expf(x - mx);
            float sm = e;
            #pragma unroll
            for (int m = 16; m >= 1; m >>= 1) sm += __shfl_xor(sm, m, 32);
            hid += s_qs[a] * (e / sm);
        }
        hid += b1;
        hid = (hid > 0.f) ? hid : expm1f(hid);
        float mx = s1;
        #pragma unroll
        for (int m = 16; m >= 1; m >>= 1) mx = fmaxf(mx, __shfl_xor(mx, m, 32));
        float e = __expf(s1 - mx);
        float ssum = e;
        #pragma unroll
        for (int m = 16; m >= 1; m >>= 1) ssum += __shfl_xor(ssum, m, 32);
        float wf = e / ssum;
        float red = hid * wf + vs * (1.f / 256.f);
        #pragma unroll
        for (int m = 16; m >= 1; m >>= 1) red += __shfl_xor(red, m, 32);
        if (tid == 0) out[b] = red;
    }
}

extern "C" void kernel_launch(void* const* d_in, const int* in_sizes, int n_in,
                              void* d_out, int out_size, void* d_ws, size_t ws_size,
                              hipStream_t stream) {
    const float* agent_qs    = (const float*)d_in[0];
    const float* entities    = (const float*)d_in[1];
    const int*   entity_mask = (const int*)  d_in[2];
    const float* fc1_w       = (const float*)d_in[3];
    const float* fc1_b       = (const float*)d_in[4];
    const float* attn_w      = (const float*)d_in[5];
    const float* out_w       = (const float*)d_in[6];
    const float* out_b       = (const float*)d_in[7];
    const float* fc2_w       = (const float*)d_in[8];
    const float* fc2_b       = (const float*)d_in[9];
    float* out = (float*)d_out;

    const int B = in_sizes[0] / NAG;  // 8192

    if (ws_size >= (size_t)(608 * 1024) && (B % SB) == 0) {
        pack_weights<<<152, 256, 0, stream>>>(fc1_w, attn_w, out_w, fc2_w, (short*)d_ws);
        flexq_mfma<<<B / SB, 256, 0, stream>>>(agent_qs, entities, entity_mask,
                                               fc1_b, out_b, fc2_b,
                                               (const short*)d_ws, out, B);
    } else {
        flexq_fp32<<<B, NTHR, 0, stream>>>(agent_qs, entities, entity_mask,
                                           fc1_w, fc1_b, attn_w, out_w, out_b,
                                           fc2_w, fc2_b, out);
    }
}